// Round 16
// baseline (67.713 us; speedup 1.0000x reference)
//
#include <hip/hip_runtime.h>
#include <math.h>

#define NFFT   1024
#define FREQ   513
#define FRAMES 256
#define SIGLEN 66560          // 256*256 + 1024
#define NB     4
#define BFT    (NB * FREQ * FRAMES)   // 525312
#define NWAVE  4               // waves per block
#define NTHR   (64 * NWAVE)    // 256
#define NCHUNK 9               // ceil(513/64)
#define NPAIR  (FRAMES / 2)    // 128 frame-pairs
#define GRIDP  (NCHUNK * NPAIR)       // 1152 blocks (LPT: desc-theta chunks)
#define MAXU   1280            // max union support (1024 + hop<=256)

typedef float f32x2 __attribute__((ext_vector_type(2)));

__device__ __forceinline__ float sigmoid_f32(float v)
{
    if (v >= 0.0f) {
        return 1.0f / (1.0f + expf(-v));
    } else {
        const float e = expf(v);
        return e / (1.0f + e);
    }
}

__device__ __forceinline__ float rfl_f32(float v)
{
    return __int_as_float(__builtin_amdgcn_readfirstlane(__float_as_int(v)));
}

// ---------------------------------------------------------------------------
// Setup: sorted-f (desc theta, stable), per-chunk theta-max, per-frame
// {base, center} tables. ws layout (bytes): sf u16[513]@0, ctmax f32[9]@1028,
// tbase i32[256]@1064, tc f32[256]@2088 -> 3112 B total.
// ---------------------------------------------------------------------------
__global__ __launch_bounds__(1024)
void dstft_setup(const float* __restrict__ raw_win,
                 const float* __restrict__ raw_hop,
                 unsigned short* __restrict__ sf,
                 float* __restrict__ ctmax,
                 int* __restrict__ tbase,
                 float* __restrict__ tc)
{
    __shared__ float th[FREQ];
    const int tid = threadIdx.x;
    if (tid < FREQ)
        th[tid] = 10.0f + sigmoid_f32(raw_win[tid]) * 1014.0f;
    __syncthreads();
    if (tid < FREQ) {
        const float ti = th[tid];
        int r = 0;
        for (int j = 0; j < FREQ; ++j) {
            const float tj = th[j];
            r += (tj > ti) || (tj == ti && j < tid);   // descending, stable
        }
        sf[r] = (unsigned short)tid;
        if ((r & 63) == 0) ctmax[r >> 6] = ti;         // chunk max (desc)
    }
    if (tid < FRAMES) {
        // f32-canonical replication of the reference pos computation
        const float hop = 1.0f + sigmoid_f32(raw_hop[0]) * 255.0f;
        float pos = (float)tid * hop;
        pos = fminf(fmaxf(pos, 0.0f), 65536.0f);
        const float fl = floorf(pos);
        tbase[tid] = (int)fl;
        tc[tid]    = 511.5f + (pos - fl);
    }
}

// ---------------------------------------------------------------------------
// FRAME-PAIRED kernel: block = (chunk, t-pair). Both frames share the
// s-coordinate DFT phasor e^{-i 2pi f s/1024}; frame-local phase recovered by
// a constant epilogue rotation e^{+i 2pi f base_k/1024}. One ds_read + one
// phasor rotation feed BOTH frames' FMAs over the support union.
// LDS: xlds 1280xfloat4 (20.5KB) aliased with part[4][64][17] -> 8 blocks/CU.
// ---------------------------------------------------------------------------
__global__ __launch_bounds__(NTHR, 8)
void dstft_main(const float* __restrict__ x,
                const float* __restrict__ raw_win,
                const float* __restrict__ raw_hop,
                const unsigned short* __restrict__ sf,   // may be null
                const float* __restrict__ ctmax,
                const int* __restrict__ tbase,
                const float* __restrict__ tc,
                float* __restrict__ out, int out_size, int stft_mode)
{
    const int tid  = threadIdx.x;
    const int lane = tid & 63;
    const int q    = tid >> 6;               // wave id = n-segment = batch

    __shared__ __align__(16) unsigned char smem[MAXU * sizeof(float4)];
    float4* xlds = reinterpret_cast<float4*>(smem);
    float (*part)[64][17] = reinterpret_cast<float (*)[64][17]>(smem);

    const int u     = (int)blockIdx.x;
    const int chunk = u >> 7;                // 0..8 (desc-theta order)
    const int tp    = u & (NPAIR - 1);
    const int t0    = 2 * tp, t1 = t0 + 1;
    const int spos  = chunk * 64 + lane;
    const bool active = (spos < FREQ);

    int   f = 0;
    float theta, tmax, c0, c1;
    int   base0, base1;

    if (sf) {
        if (active) {
            f = (int)sf[spos];
            f = (f < 0) ? 0 : ((f > FREQ - 1) ? (FREQ - 1) : f);
        }
        theta = active ? (10.0f + sigmoid_f32(raw_win[f]) * 1014.0f) : 10.0f;
        tmax  = rfl_f32(ctmax[chunk]);
        base0 = __builtin_amdgcn_readfirstlane(tbase[t0]);
        base1 = __builtin_amdgcn_readfirstlane(tbase[t1]);
        c0    = rfl_f32(tc[t0]);
        c1    = rfl_f32(tc[t1]);
    } else {
        if (active) f = spos;
        theta = active ? (10.0f + sigmoid_f32(raw_win[f]) * 1014.0f) : 10.0f;
        float tmaxv = theta;
#pragma unroll
        for (int s = 32; s; s >>= 1)
            tmaxv = fmaxf(tmaxv, __shfl_xor(tmaxv, s, 64));
        tmax = rfl_f32(tmaxv);
        const float hop = 1.0f + sigmoid_f32(raw_hop[0]) * 255.0f;
        float pos0 = fminf(fmaxf((float)t0 * hop, 0.0f), 65536.0f);
        float pos1 = fminf(fmaxf((float)t1 * hop, 0.0f), 65536.0f);
        const float fl0 = floorf(pos0), fl1 = floorf(pos1);
        base0 = __builtin_amdgcn_readfirstlane((int)fl0);
        base1 = __builtin_amdgcn_readfirstlane((int)fl1);
        c0    = rfl_f32(511.5f + (pos0 - fl0));
        c1    = rfl_f32(511.5f + (pos1 - fl1));
    }

    // frame-local supports, clamped to [0,1023]; union in global s-coords
    int lo0 = (int)floorf(c0 - 0.5f * tmax);
    int hi1 = (int)ceilf (c1 + 0.5f * tmax);
    lo0 = lo0 > 0 ? lo0 : 0;
    hi1 = hi1 < (NFFT - 1) ? hi1 : (NFFT - 1);
    int gmin = base0 + lo0;
    int gmax = base1 + hi1;
    int cntU = gmax - gmin + 1;
    cntU = cntU < 1 ? 1 : (cntU > MAXU ? MAXU : cntU);
    gmin = __builtin_amdgcn_readfirstlane(gmin);
    cntU = __builtin_amdgcn_readfirstlane(cntU);

    // ---- stage x[gmin .. gmin+cntU) x 4 batches into LDS ----
    for (int n = tid; n < cntU; n += NTHR) {
        float4 v;
        v.x = x[gmin + n];
        v.y = x[gmin + n + SIGLEN];
        v.z = x[gmin + n + 2 * SIGLEN];
        v.w = x[gmin + n + 3 * SIGLEN];
        xlds[n] = v;
    }
    __syncthreads();

    const int si     = (cntU * q) / NWAVE;
    const int si1    = (cntU * (q + 1)) / NWAVE;
    const int segcnt = si1 - si;
    const int sg     = gmin + si;            // global start sample (scalar)

    const float invth = 1.0f / theta;
    // window args in frame-local coords (no 66k-magnitude cancellation)
    float r0 = ((float)(sg - base0) - c0) * invth;
    float r1 = ((float)(sg - base1) - c1) * invth;

    // shared phasor p = {cos, sin}(2*pi*f*s/1024), step +f/1024 rev
    const float sdr = (float)f * (1.0f / 1024.0f);
    const float cd  = __builtin_amdgcn_cosf(sdr);
    const float sd  = __builtin_amdgcn_sinf(sdr);
    int m0 = (f * sg) & (NFFT - 1);
    m0 = (m0 >= 512) ? (m0 - 1024) : m0;
    const float p0 = (float)m0 * (1.0f / 1024.0f);

    f32x2 p;
    p.x = __builtin_amdgcn_cosf(p0);
    p.y = __builtin_amdgcn_sinf(p0);
    const f32x2 cdv = { cd,  cd };
    const f32x2 sdv = { -sd, sd };

    // accumulators: per frame {cr,sr} x batch-pairs {b0,b1},{b2,b3}
    f32x2 cr0a = {0,0}, cr0b = {0,0}, sr0a = {0,0}, sr0b = {0,0};
    f32x2 cr1a = {0,0}, cr1b = {0,0}, sr1a = {0,0}, sr1b = {0,0};

    const float4* __restrict__ xp = &xlds[si];
#pragma unroll 2
    for (int i = 0; i < segcnt; ++i) {
        // windows: med3 clamp -> cos(+-0.5 rev) = -1 -> w = 0 outside
        const float rc0 = __builtin_amdgcn_fmed3f(r0, -0.5f, 0.5f);
        const float w0  = fmaf(0.5f, __builtin_amdgcn_cosf(rc0), 0.5f);
        const float rc1 = __builtin_amdgcn_fmed3f(r1, -0.5f, 0.5f);
        const float w1  = fmaf(0.5f, __builtin_amdgcn_cosf(rc1), 0.5f);
        const float4 v = xp[i];               // ds_read_b128 (shared)
        const f32x2 va = { v.x, v.y };
        const f32x2 vb = { v.z, v.w };
        const float wc0 = w0 * p.x, ws0 = w0 * p.y;
        const float wc1 = w1 * p.x, ws1 = w1 * p.y;
        const f32x2 wc0v = { wc0, wc0 }, ws0v = { ws0, ws0 };
        const f32x2 wc1v = { wc1, wc1 }, ws1v = { ws1, ws1 };
        cr0a = __builtin_elementwise_fma(va, wc0v, cr0a);
        cr0b = __builtin_elementwise_fma(vb, wc0v, cr0b);
        sr0a = __builtin_elementwise_fma(va, ws0v, sr0a);
        sr0b = __builtin_elementwise_fma(vb, ws0v, sr0b);
        cr1a = __builtin_elementwise_fma(va, wc1v, cr1a);
        cr1b = __builtin_elementwise_fma(vb, wc1v, cr1b);
        sr1a = __builtin_elementwise_fma(va, ws1v, sr1a);
        sr1b = __builtin_elementwise_fma(vb, ws1v, sr1b);
        const f32x2 ps = p.yx;
        p = __builtin_elementwise_fma(p, cdv, ps * sdv);   // shared rotate
        r0 += invth;
        r1 += invth;
    }

    // ---- cross-wave combine; part aliases xlds, fence reads first ----
    __syncthreads();
    part[q][lane][0]  = cr0a.x;  part[q][lane][1]  = cr0a.y;
    part[q][lane][2]  = cr0b.x;  part[q][lane][3]  = cr0b.y;
    part[q][lane][4]  = sr0a.x;  part[q][lane][5]  = sr0a.y;
    part[q][lane][6]  = sr0b.x;  part[q][lane][7]  = sr0b.y;
    part[q][lane][8]  = cr1a.x;  part[q][lane][9]  = cr1a.y;
    part[q][lane][10] = cr1b.x;  part[q][lane][11] = cr1b.y;
    part[q][lane][12] = sr1a.x;  part[q][lane][13] = sr1a.y;
    part[q][lane][14] = sr1b.x;  part[q][lane][15] = sr1b.y;
    __syncthreads();

    // ---- epilogue: thread = (lane, batch=q); both frames ----
    if (active) {
#pragma unroll
        for (int k = 0; k < 2; ++k) {
            float cr = 0.f, sr = 0.f;
#pragma unroll
            for (int pw = 0; pw < NWAVE; ++pw) {
                cr += part[pw][lane][8 * k + q];
                sr += part[pw][lane][8 * k + 4 + q];
            }
            // rotate by phi = 2*pi*f*base_k/1024: re=CRn, im=-SRn recovery
            const int bk = k ? base1 : base0;
            int mk = (f * bk) & (NFFT - 1);
            mk = (mk >= 512) ? (mk - 1024) : mk;
            const float ph = (float)mk * (1.0f / 1024.0f);
            const float cph = __builtin_amdgcn_cosf(ph);
            const float sph = __builtin_amdgcn_sinf(ph);
            const float re = cr * cph + sr * sph;
            const float im = cr * sph - sr * cph;
            const int tk  = k ? t1 : t0;
            const int idx = q * (FREQ * FRAMES) + f * FRAMES + tk;
            if (idx < out_size)
                out[idx] = sqrtf(fmaf(re, re, im * im)) + 1e-12f;   // spec
            if (stft_mode == 2) {
                if (BFT + 2 * idx + 1 < out_size) {
                    out[BFT + 2 * idx]     = re;
                    out[BFT + 2 * idx + 1] = im;
                }
            } else {
                if (BFT + idx < out_size)
                    out[BFT + idx] = re;     // complex stored as f32 real
            }
        }
    }
}

// ---------------------------------------------------------------------------
extern "C" void kernel_launch(void* const* d_in, const int* in_sizes, int n_in,
                              void* d_out, int out_size, void* d_ws, size_t ws_size,
                              hipStream_t stream)
{
    const float* x       = (const float*)d_in[0];
    const float* raw_win = (const float*)d_in[1];
    const float* raw_hop = (const float*)d_in[2];
    float* out = (float*)d_out;

    unsigned short* sf    = nullptr;
    float*          ctmax = nullptr;
    int*            tbase = nullptr;
    float*          tc    = nullptr;
    if (d_ws != nullptr && ws_size >= 3200) {
        sf    = (unsigned short*)d_ws;                   // 1028 B
        ctmax = (float*)((char*)d_ws + 1028);            // 36 B
        tbase = (int*)  ((char*)d_ws + 1064);            // 1024 B
        tc    = (float*)((char*)d_ws + 2088);            // 1024 B (end 3112)
        dstft_setup<<<1, 1024, 0, stream>>>(raw_win, raw_hop,
                                            sf, ctmax, tbase, tc);
    }
    const int stft_mode = (out_size >= 3 * BFT) ? 2 : 1;
    dstft_main<<<GRIDP, NTHR, 0, stream>>>(
        x, raw_win, raw_hop, sf, ctmax, tbase, tc, out, out_size, stft_mode);
}

// Round 17
// 56.940 us; speedup vs baseline: 1.1892x; 1.1892x over previous
//
#include <hip/hip_runtime.h>
#include <math.h>

#define NFFT   1024
#define FREQ   513
#define FRAMES 256
#define SIGLEN 66560          // 256*256 + 1024
#define NB     4
#define BFT    (NB * FREQ * FRAMES)   // 525312
#define NWAVE  4               // waves per block (n-loop split factor)
#define NTHR   (64 * NWAVE)    // 256
#define NCHUNK 9               // ceil(513/64)
#define UNITS  (NCHUNK * FRAMES)      // 2304 blocks, 1 unit each (LPT order)

typedef float f32x2 __attribute__((ext_vector_type(2)));

__device__ __forceinline__ float sigmoid_f32(float v)
{
    if (v >= 0.0f) {
        return 1.0f / (1.0f + expf(-v));
    } else {
        const float e = expf(v);
        return e / (1.0f + e);
    }
}

__device__ __forceinline__ float rfl_f32(float v)
{
    return __int_as_float(__builtin_amdgcn_readfirstlane(__float_as_int(v)));
}

// ---------------------------------------------------------------------------
// Setup: sorted-f (desc theta, stable), per-chunk theta-max, per-frame
// {base, center} tables. ws layout (bytes): sf u16[513]@0, ctmax f32[9]@1028,
// tbase i32[256]@1064, tc f32[256]@2088 -> 3112 B total.
// ---------------------------------------------------------------------------
__global__ __launch_bounds__(1024)
void dstft_setup(const float* __restrict__ raw_win,
                 const float* __restrict__ raw_hop,
                 unsigned short* __restrict__ sf,
                 float* __restrict__ ctmax,
                 int* __restrict__ tbase,
                 float* __restrict__ tc)
{
    __shared__ float th[FREQ];
    const int tid = threadIdx.x;
    if (tid < FREQ)
        th[tid] = 10.0f + sigmoid_f32(raw_win[tid]) * 1014.0f;
    __syncthreads();
    if (tid < FREQ) {
        const float ti = th[tid];
        int r = 0;
        for (int j = 0; j < FREQ; ++j) {
            const float tj = th[j];
            r += (tj > ti) || (tj == ti && j < tid);   // descending, stable
        }
        sf[r] = (unsigned short)tid;
        if ((r & 63) == 0) ctmax[r >> 6] = ti;         // chunk max (desc)
    }
    if (tid < FRAMES) {
        // f32-canonical replication of the reference pos computation
        const float hop = 1.0f + sigmoid_f32(raw_hop[0]) * 255.0f;
        float pos = (float)tid * hop;
        pos = fminf(fmaxf(pos, 0.0f), 65536.0f);
        const float fl = floorf(pos);
        tbase[tid] = (int)fl;
        tc[tid]    = 511.5f + (pos - fl);
    }
}

// ---------------------------------------------------------------------------
// r13 shell: 2304 blocks (LPT desc-theta order), 4 waves, ONE unit each.
// x staged into LDS float4 rows over [lo,hi]; part[] aliases xlds.
// Inner loop: unroll-8 (8 ds_read_b128 in flight > ~120cy LDS latency),
// flat window-arg within group (only the phasor is loop-carried).
// ---------------------------------------------------------------------------
__global__ __launch_bounds__(NTHR, 8)
void dstft_main(const float* __restrict__ x,
                const float* __restrict__ raw_win,
                const float* __restrict__ raw_hop,
                const unsigned short* __restrict__ sf,   // may be null
                const float* __restrict__ ctmax,
                const int* __restrict__ tbase,
                const float* __restrict__ tc,
                float* __restrict__ out, int out_size, int stft_mode)
{
    const int tid  = threadIdx.x;
    const int lane = tid & 63;
    const int q    = tid >> 6;               // wave id = n-segment = batch

    __shared__ __align__(16) unsigned char smem[NFFT * sizeof(float4)]; //16KB
    float4* xlds = reinterpret_cast<float4*>(smem);
    float (*part)[64][9] = reinterpret_cast<float (*)[64][9]>(smem);

    const int u     = (int)blockIdx.x;
    const int chunk = u >> 8;                // 0..8 (desc-theta order)
    const int t     = u & 255;
    const int spos  = chunk * 64 + lane;
    const bool active = (spos < FREQ);

    int   f = 0;
    float theta, tmax, c;
    int   base;

    if (sf) {
        if (active) {
            f = (int)sf[spos];
            f = (f < 0) ? 0 : ((f > FREQ - 1) ? (FREQ - 1) : f);
        }
        theta = active ? (10.0f + sigmoid_f32(raw_win[f]) * 1014.0f) : 10.0f;
        tmax  = rfl_f32(ctmax[chunk]);
        base  = __builtin_amdgcn_readfirstlane(tbase[t]);
        c     = rfl_f32(tc[t]);
    } else {
        // fallback (no ws): natural f order, inline params
        if (active) f = spos;
        theta = active ? (10.0f + sigmoid_f32(raw_win[f]) * 1014.0f) : 10.0f;
        float tmaxv = theta;
#pragma unroll
        for (int s = 32; s; s >>= 1)
            tmaxv = fmaxf(tmaxv, __shfl_xor(tmaxv, s, 64));
        tmax = rfl_f32(tmaxv);
        const float hop = 1.0f + sigmoid_f32(raw_hop[0]) * 255.0f;
        float pos = (float)t * hop;
        pos = fminf(fmaxf(pos, 0.0f), 65536.0f);
        const float fl = floorf(pos);
        base = __builtin_amdgcn_readfirstlane((int)fl);
        c    = rfl_f32(511.5f + (pos - fl));
    }

    int lo = (int)floorf(c - 0.5f * tmax);
    int hi = (int)ceilf (c + 0.5f * tmax);
    lo = lo > 0 ? lo : 0;
    hi = hi < (NFFT - 1) ? hi : (NFFT - 1);
    int cnt = hi - lo + 1;
    cnt = cnt < 0 ? 0 : (cnt > NFFT ? NFFT : cnt);
    lo  = __builtin_amdgcn_readfirstlane(lo);
    cnt = __builtin_amdgcn_readfirstlane(cnt);

    // ---- stage x tile [lo, lo+cnt) into LDS (coalesced, loads batched) ----
#pragma unroll 4
    for (int n = lo + tid; n < lo + cnt; n += NTHR) {
        float4 v;
        v.x = x[base + n];
        v.y = x[base + n + SIGLEN];
        v.z = x[base + n + 2 * SIGLEN];
        v.w = x[base + n + 3 * SIGLEN];
        xlds[n - lo] = v;
    }
    __syncthreads();

    const int s0     = lo + (cnt * q) / NWAVE;
    const int s1     = lo + (cnt * (q + 1)) / NWAVE;
    const int segcnt = s1 - s0;

    const float invth = 1.0f / theta;
    float r = ((float)s0 - c) * invth;       // window arg, revolutions

    // phasor init at n=s0 and step: exact int reduction + hw trig (rev)
    const float sdr = (float)f * (1.0f / 1024.0f);
    const float cd  = __builtin_amdgcn_cosf(sdr);
    const float sd  = __builtin_amdgcn_sinf(sdr);
    int m0 = (f * s0) & (NFFT - 1);
    m0 = (m0 >= 512) ? (m0 - 1024) : m0;
    const float p0 = (float)m0 * (1.0f / 1024.0f);

    f32x2 p;                                  // {ca, sa}
    p.x = __builtin_amdgcn_cosf(p0);
    p.y = __builtin_amdgcn_sinf(p0);
    const f32x2 cdv = { cd,  cd };
    const f32x2 sdv = { -sd, sd };

    // batch-packed accumulators: {b0,b1} and {b2,b3} for re and im-sum
    f32x2 are01 = {0.f, 0.f}, are23 = {0.f, 0.f};
    f32x2 aim01 = {0.f, 0.f}, aim23 = {0.f, 0.f};

    const float4* __restrict__ xp = &xlds[s0 - lo];

    int i = 0;
    for (; i + 8 <= segcnt; i += 8) {
#pragma unroll
        for (int k = 0; k < 8; ++k) {
            // flat window arg (independent across unrolled iters)
            const float rk = fmaf((float)k, invth, r);
            const float rc = __builtin_amdgcn_fmed3f(rk, -0.5f, 0.5f);
            const float w  = fmaf(0.5f, __builtin_amdgcn_cosf(rc), 0.5f);
            const float wc  = w * p.x;
            const float wsn = w * p.y;
            const f32x2 wcv = { wc,  wc  };
            const f32x2 wsv = { wsn, wsn };
            const float4 v = xp[i + k];       // 8 b128 reads in flight
            const f32x2 v01 = { v.x, v.y };
            const f32x2 v23 = { v.z, v.w };
            are01 = __builtin_elementwise_fma(v01, wcv, are01);
            are23 = __builtin_elementwise_fma(v23, wcv, are23);
            aim01 = __builtin_elementwise_fma(v01, wsv, aim01);
            aim23 = __builtin_elementwise_fma(v23, wsv, aim23);
            const f32x2 ps = p.yx;
            p = __builtin_elementwise_fma(p, cdv, ps * sdv);   // rotate
        }
        r = fmaf(8.0f, invth, r);
    }
    for (; i < segcnt; ++i) {                 // tail
        const float rc = __builtin_amdgcn_fmed3f(r, -0.5f, 0.5f);
        const float w  = fmaf(0.5f, __builtin_amdgcn_cosf(rc), 0.5f);
        const float wc  = w * p.x;
        const float wsn = w * p.y;
        const f32x2 wcv = { wc,  wc  };
        const f32x2 wsv = { wsn, wsn };
        const float4 v = xp[i];
        const f32x2 v01 = { v.x, v.y };
        const f32x2 v23 = { v.z, v.w };
        are01 = __builtin_elementwise_fma(v01, wcv, are01);
        are23 = __builtin_elementwise_fma(v23, wcv, are23);
        aim01 = __builtin_elementwise_fma(v01, wsv, aim01);
        aim23 = __builtin_elementwise_fma(v23, wsv, aim23);
        const f32x2 ps = p.yx;
        p = __builtin_elementwise_fma(p, cdv, ps * sdv);
        r += invth;
    }

    // ---- cross-wave combine; part aliases xlds, fence reads first ----
    __syncthreads();
    part[q][lane][0] = are01.x;  part[q][lane][1] = are01.y;
    part[q][lane][2] = are23.x;  part[q][lane][3] = are23.y;
    part[q][lane][4] = aim01.x;  part[q][lane][5] = aim01.y;
    part[q][lane][6] = aim23.x;  part[q][lane][7] = aim23.y;
    __syncthreads();

    // ---- epilogue: 4 waves in parallel, thread = (lane, batch=q) ----
    if (active) {
        float res = 0.f, sms = 0.f;
#pragma unroll
        for (int pw = 0; pw < NWAVE; ++pw) {
            res += part[pw][lane][q];
            sms += part[pw][lane][4 + q];
        }
        const float re = res;
        const float im = -sms;
        const int idx = q * (FREQ * FRAMES) + f * FRAMES + t;
        if (idx < out_size)
            out[idx] = sqrtf(fmaf(re, re, im * im)) + 1e-12f;   // spec
        if (stft_mode == 2) {
            if (BFT + 2 * idx + 1 < out_size) {
                out[BFT + 2 * idx]     = re;
                out[BFT + 2 * idx + 1] = im;
            }
        } else {
            if (BFT + idx < out_size)
                out[BFT + idx] = re;         // complex stored as f32 real
        }
    }
}

// ---------------------------------------------------------------------------
extern "C" void kernel_launch(void* const* d_in, const int* in_sizes, int n_in,
                              void* d_out, int out_size, void* d_ws, size_t ws_size,
                              hipStream_t stream)
{
    const float* x       = (const float*)d_in[0];
    const float* raw_win = (const float*)d_in[1];
    const float* raw_hop = (const float*)d_in[2];
    float* out = (float*)d_out;

    unsigned short* sf    = nullptr;
    float*          ctmax = nullptr;
    int*            tbase = nullptr;
    float*          tc    = nullptr;
    if (d_ws != nullptr && ws_size >= 3200) {
        sf    = (unsigned short*)d_ws;                   // 1028 B
        ctmax = (float*)((char*)d_ws + 1028);            // 36 B
        tbase = (int*)  ((char*)d_ws + 1064);            // 1024 B
        tc    = (float*)((char*)d_ws + 2088);            // 1024 B (end 3112)
        dstft_setup<<<1, 1024, 0, stream>>>(raw_win, raw_hop,
                                            sf, ctmax, tbase, tc);
    }
    const int stft_mode = (out_size >= 3 * BFT) ? 2 : 1;
    dstft_main<<<UNITS, NTHR, 0, stream>>>(
        x, raw_win, raw_hop, sf, ctmax, tbase, tc, out, out_size, stft_mode);
}